// Round 8
// baseline (4037.975 us; speedup 1.0000x reference)
//
#include <hip/hip_runtime.h>

#define NNODE 50000
#define NEDGE 800000
#define NLAYER 4
#define BN_EPS 1e-5f

#define NH (NNODE*64)   // 3,200,000
#define NE (NEDGE*64)   // 51,200,000

typedef __attribute__((ext_vector_type(8))) short short8v;

__device__ __forceinline__ float sigf(float x){ return 1.0f/(1.0f+__expf(-x)); }

__device__ __forceinline__ float bf2f(unsigned short u){
  union { unsigned int i; float f; } c; c.i = ((unsigned int)u)<<16; return c.f;
}
__device__ __forceinline__ unsigned short f2bf(float f){
  union { float f; unsigned int i; } c; c.f = f;
  unsigned int r = c.i + 0x7FFFu + ((c.i>>16)&1u);   // RNE (finite values)
  return (unsigned short)(r>>16);
}

// ---------------------------------------------------------------- utility
__global__ void k_zero_i(int* __restrict__ p, int n){
  int i = blockIdx.x*256 + threadIdx.x;
  if(i<n) p[i]=0;
}
__global__ void k_zero_stats(float* __restrict__ stats){
  stats[threadIdx.x] = 0.f;   // one block of 256
}
__global__ void k_count(const int* __restrict__ ei, int* __restrict__ cnt){
  int i = blockIdx.x*256 + threadIdx.x;
  if(i<NEDGE) atomicAdd(&cnt[ei[i]], 1);   // ei[0][i] = dst
}
__global__ void k_inv(const int* __restrict__ cnt, float* __restrict__ invc){
  int i = blockIdx.x*256 + threadIdx.x;
  if(i<NNODE){ int c=cnt[i]; invc[i] = 1.0f/(float)(c<1?1:c); }
}

// single-block exclusive scan of cnt -> row_ptr (+cursor copy); row_ptr[NNODE]=total
__global__ void k_scan(const int* __restrict__ cnt, int* __restrict__ row_ptr,
                       int* __restrict__ cursor){
  __shared__ int buf[256];
  __shared__ int carry;
  const int tid = threadIdx.x;
  if(tid==0) carry=0;
  __syncthreads();
  for(int base=0; base<NNODE; base+=256){
    int i = base+tid;
    int v = (i<NNODE)? cnt[i] : 0;
    buf[tid]=v; __syncthreads();
    #pragma unroll
    for(int off=1; off<256; off<<=1){
      int t = (tid>=off)? buf[tid-off] : 0;
      __syncthreads();
      buf[tid]+=t;
      __syncthreads();
    }
    int excl = carry + buf[tid]-v;
    if(i<NNODE){ row_ptr[i]=excl; cursor[i]=excl; }
    __syncthreads();
    if(tid==0) carry += buf[255];
    __syncthreads();
  }
  if(tid==0) row_ptr[NNODE]=carry;
}

// slot p (dst-sorted order) <- original edge id
__global__ void k_fill(const int* __restrict__ ei, int* __restrict__ cursor,
                       int* __restrict__ eidP){
  int i = blockIdx.x*256 + threadIdx.x;
  if(i<NEDGE){
    int pos = atomicAdd(&cursor[ei[i]], 1);
    eidP[pos] = i;
  }
}

// pre-gather dst/src per slot
__global__ void k_perm(const int* __restrict__ ei, const int* __restrict__ eidP,
                       int* __restrict__ dstP, int* __restrict__ srcP){
  int p = blockIdx.x*256 + threadIdx.x;
  if(p<NEDGE){
    int eid = eidP[p];
    dstP[p] = ei[eid];
    srcP[p] = ei[NEDGE+eid];
  }
}

__global__ void k_init_h(const float* __restrict__ x, const float* __restrict__ w,
                         const float* __restrict__ b, float* __restrict__ h){
  int t = blockIdx.x*256 + threadIdx.x;
  if(t>=NH) return;
  int i=t>>6, j=t&63;
  float v = x[2*i]*w[j] + x[2*i+1]*w[64+j] + b[j];
  h[t] = fmaxf(v, 0.0f);
}

// e stored in slot (dst-sorted) order: e[slot] = relu(ea[eidP[slot]]*w + b)
__global__ void k_init_e(const float* __restrict__ ea, const int* __restrict__ eidP,
                         const float* __restrict__ w, const float* __restrict__ b,
                         unsigned short* __restrict__ e){
  int t = blockIdx.x*256 + threadIdx.x;      // pair index
  if(t >= NE/2) return;
  int p = t>>5;          // slot
  int j = (t&31)<<1;
  float a = ea[eidP[p]];
  float v0 = fmaxf(a*w[j]   + b[j],   0.f);
  float v1 = fmaxf(a*w[j+1] + b[j+1], 0.f);
  unsigned int pk = (unsigned int)f2bf(v0) | ((unsigned int)f2bf(v1)<<16);
  *reinterpret_cast<unsigned int*>(&e[2*t]) = pk;
}

// ------------------------------------------------------------ tile helpers
__device__ __forceinline__ void tile_gemm(const float (&At)[64][68], const float (&Ws)[64][68],
                                          int r0, int c0, float (&acc)[4][4]){
  #pragma unroll 4
  for(int k=0;k<64;++k){
    const float4 a = *reinterpret_cast<const float4*>(&At[k][r0]);
    const float4 b = *reinterpret_cast<const float4*>(&Ws[k][c0]);
    const float av[4]={a.x,a.y,a.z,a.w};
    const float bv[4]={b.x,b.y,b.z,b.w};
    #pragma unroll
    for(int ri=0;ri<4;++ri)
      #pragma unroll
      for(int ci=0;ci<4;++ci)
        acc[ri][ci] = fmaf(av[ri], bv[ci], acc[ri][ci]);
  }
}

__device__ __forceinline__ void stage_At_f32(float (&At)[64][68], const float* __restrict__ src,
                                             int row0, int rowmax, int tid){
  for(int it=0; it<4; ++it){
    int idx = tid + it*256;
    int r = idx>>4, c4=(idx&15)<<2;
    int gr = row0 + r;
    float4 v = make_float4(0.f,0.f,0.f,0.f);
    if(gr < rowmax) v = *reinterpret_cast<const float4*>(&src[(size_t)gr*64 + c4]);
    At[c4+0][r]=v.x; At[c4+1][r]=v.y; At[c4+2][r]=v.z; At[c4+3][r]=v.w;
  }
}

__device__ __forceinline__ void stage_At_bf16(float (&At)[64][68], const unsigned short* __restrict__ src,
                                              int row0, int tid){
  #pragma unroll
  for(int it=0; it<2; ++it){
    int idx = tid + it*256;          // 0..511
    int r = idx>>3, c8 = (idx&7)<<3;
    int gr = row0 + r;
    const short8v v = *reinterpret_cast<const short8v*>(&src[(size_t)gr*64 + c8]);
    #pragma unroll
    for(int j=0;j<8;++j) At[c8+j][r] = bf2f((unsigned short)v[j]);
  }
}

__device__ __forceinline__ void stage_W(float (&Ws)[64][68], const float* __restrict__ W, int tid){
  for(int it=0; it<4; ++it){
    int idx = tid + it*256;
    int k = idx>>4, c4=(idx&15)<<2;
    *reinterpret_cast<float4*>(&Ws[k][c4]) = *reinterpret_cast<const float4*>(&W[k*64+c4]);
  }
}

// ---------------------------------------------------------- node GEMMs (U,V,B,C)
__device__ __forceinline__ void node_one_mat(float (&At)[64][68], float (&Ws)[64][68],
    const float* __restrict__ W, const float* __restrict__ B, float* __restrict__ O,
    int row0, int tid){
  __syncthreads();
  stage_W(Ws, W, tid);
  __syncthreads();
  const int tx=tid&15, ty=tid>>4, r0=tx<<2, c0=ty<<2;
  float acc[4][4]={{0.f}};
  tile_gemm(At, Ws, r0, c0, acc);
  const float4 b4 = *reinterpret_cast<const float4*>(&B[c0]);
  const float bb[4]={b4.x,b4.y,b4.z,b4.w};
  #pragma unroll
  for(int ri=0;ri<4;++ri){
    int gr = row0 + r0 + ri;
    if(gr < NNODE){
      float4 o = make_float4(acc[ri][0]+bb[0], acc[ri][1]+bb[1],
                             acc[ri][2]+bb[2], acc[ri][3]+bb[3]);
      *reinterpret_cast<float4*>(&O[(size_t)gr*64 + c0]) = o;
    }
  }
}

__global__ __launch_bounds__(256) void k_node_gemm(
    const float* __restrict__ h,
    const float* __restrict__ Uw, const float* __restrict__ Ub,
    const float* __restrict__ Vw, const float* __restrict__ Vb,
    const float* __restrict__ Bw, const float* __restrict__ Bb,
    const float* __restrict__ Cw, const float* __restrict__ Cb,
    float* __restrict__ Uh, float* __restrict__ Vh,
    float* __restrict__ Bh, float* __restrict__ Ch)
{
  __shared__ float At[64][68];
  __shared__ float Ws[64][68];
  const int tid = threadIdx.x;
  const int row0 = blockIdx.x*64;
  stage_At_f32(At, h, row0, NNODE, tid);
  node_one_mat(At, Ws, Uw, Ub, Uh, row0, tid);
  node_one_mat(At, Ws, Vw, Vb, Vh, row0, tid);
  node_one_mat(At, Ws, Bw, Bb, Bh, row0, tid);
  node_one_mat(At, Ws, Cw, Cb, Ch, row0, tid);
}

// ---------------------------------------------------------- edge pass A
// slots are dst-sorted; t = e@Aw + Ab + Bh[dstP] + Ch[srcP]; e-BN stats only.
__global__ __launch_bounds__(256) void k_edge_A(
    const unsigned short* __restrict__ e,
    const float* __restrict__ Aw, const float* __restrict__ Ab,
    const float* __restrict__ Bh, const float* __restrict__ Ch,
    const int* __restrict__ dstP, const int* __restrict__ srcP,
    float* __restrict__ stats)
{
  __shared__ float At[64][68];
  __shared__ float Ws[64][68];
  __shared__ float red[128];
  const int tid=threadIdx.x;
  const int row0 = blockIdx.x*64;
  if(tid<128) red[tid]=0.f;
  stage_At_bf16(At, e, row0, tid);
  stage_W(Ws, Aw, tid);
  __syncthreads();
  const int tx=tid&15, ty=tid>>4, r0=tx<<2, c0=ty<<2;
  float acc[4][4]={{0.f}};
  tile_gemm(At, Ws, r0, c0, acc);

  int dstI[4], srcI[4];
  #pragma unroll
  for(int ri=0;ri<4;++ri){
    dstI[ri]=dstP[row0+r0+ri];
    srcI[ri]=srcP[row0+r0+ri];
  }
  const float4 ab4 = *reinterpret_cast<const float4*>(&Ab[c0]);
  const float ab[4]={ab4.x,ab4.y,ab4.z,ab4.w};

  float s1[4]={0.f,0.f,0.f,0.f}, s2[4]={0.f,0.f,0.f,0.f};
  #pragma unroll
  for(int ri=0;ri<4;++ri){
    const float4 bh4 = *reinterpret_cast<const float4*>(&Bh[(size_t)dstI[ri]*64 + c0]);
    const float4 ch4 = *reinterpret_cast<const float4*>(&Ch[(size_t)srcI[ri]*64 + c0]);
    const float bh[4]={bh4.x,bh4.y,bh4.z,bh4.w};
    const float ch[4]={ch4.x,ch4.y,ch4.z,ch4.w};
    #pragma unroll
    for(int ci=0;ci<4;++ci){
      float t = acc[ri][ci] + ab[ci] + bh[ci] + ch[ci];
      s1[ci]+=t; s2[ci]+=t*t;
    }
  }
  #pragma unroll
  for(int ci=0;ci<4;++ci){
    atomicAdd(&red[c0+ci],    s1[ci]);
    atomicAdd(&red[64+c0+ci], s2[ci]);
  }
  __syncthreads();
  if(tid<64){
    atomicAdd(&stats[tid],    red[tid]);
    atomicAdd(&stats[64+tid], red[64+tid]);
  }
}

// ---------------------------------------------------------- CSR aggregation + h-BN stats
// one wave per node; lane = channel; e rows for node are CONTIGUOUS slots
__global__ __launch_bounds__(256) void k_agg(
    const unsigned short* __restrict__ e,
    const float* __restrict__ Vh,
    const int* __restrict__ srcP,
    const int* __restrict__ row_ptr,
    const float* __restrict__ invc,
    float* __restrict__ Uh, float* __restrict__ stats)
{
  __shared__ float red[128];
  const int tid=threadIdx.x;
  if(tid<128) red[tid]=0.f;
  __syncthreads();
  const int lane = tid&63;
  const int node = blockIdx.x*4 + (tid>>6);   // 4 waves/block, NNODE%4==0
  const int beg = row_ptr[node];
  const int end = row_ptr[node+1];
  float acc = 0.f;
  for(int p=beg; p<end; ++p){
    int src = srcP[p];
    float g = sigf(bf2f(e[(size_t)p*64 + lane]));
    acc = fmaf(g, Vh[(size_t)src*64 + lane], acc);
  }
  size_t o = (size_t)node*64 + lane;
  float val = Uh[o] + acc*invc[node];
  Uh[o] = val;
  atomicAdd(&red[lane], val);
  atomicAdd(&red[64+lane], val*val);
  __syncthreads();
  if(tid<128) atomicAdd(&stats[128+tid], red[tid]);
}

__global__ void k_node_finB(const float* __restrict__ th, float* __restrict__ h,
                            const float* __restrict__ stats,
                            const float* __restrict__ hg, const float* __restrict__ hb){
  int t = blockIdx.x*256 + threadIdx.x;
  if(t>=NH) return;
  int j=t&63;
  const float invN = 1.0f/(float)NNODE;
  float mean = stats[128+j]*invN;
  float var  = stats[192+j]*invN - mean*mean;
  float rstd = rsqrtf(var + BN_EPS);
  float v = (th[t]-mean)*rstd*hg[j] + hb[j];
  h[t] += fmaxf(v, 0.0f);
}

// ---------------------------------------------------------- edge pass B
__global__ __launch_bounds__(256) void k_edge_B(
    unsigned short* __restrict__ e,
    const float* __restrict__ Aw, const float* __restrict__ Ab,
    const float* __restrict__ Bh, const float* __restrict__ Ch,
    const int* __restrict__ dstP, const int* __restrict__ srcP,
    const float* __restrict__ stats,
    const float* __restrict__ eg, const float* __restrict__ eb)
{
  __shared__ float At[64][68];
  __shared__ float Ws[64][68];
  const int tid=threadIdx.x;
  const int row0 = blockIdx.x*64;
  stage_At_bf16(At, e, row0, tid);
  stage_W(Ws, Aw, tid);
  __syncthreads();
  const int tx=tid&15, ty=tid>>4, r0=tx<<2, c0=ty<<2;
  float acc[4][4]={{0.f}};
  tile_gemm(At, Ws, r0, c0, acc);

  int dstI[4], srcI[4];
  #pragma unroll
  for(int ri=0;ri<4;++ri){
    dstI[ri]=dstP[row0+r0+ri];
    srcI[ri]=srcP[row0+r0+ri];
  }
  const float4 ab4 = *reinterpret_cast<const float4*>(&Ab[c0]);
  const float ab[4]={ab4.x,ab4.y,ab4.z,ab4.w};
  const float invE = 1.0f/(float)NEDGE;
  const float4 s14 = *reinterpret_cast<const float4*>(&stats[c0]);
  const float4 s24 = *reinterpret_cast<const float4*>(&stats[64+c0]);
  const float4 gg4 = *reinterpret_cast<const float4*>(&eg[c0]);
  const float4 bb4 = *reinterpret_cast<const float4*>(&eb[c0]);
  float mean[4], rstd[4], gg[4], bb[4];
  {
    const float s1v[4]={s14.x,s14.y,s14.z,s14.w};
    const float s2v[4]={s24.x,s24.y,s24.z,s24.w};
    const float ggv[4]={gg4.x,gg4.y,gg4.z,gg4.w};
    const float bbv[4]={bb4.x,bb4.y,bb4.z,bb4.w};
    #pragma unroll
    for(int ci=0;ci<4;++ci){
      mean[ci]=s1v[ci]*invE;
      float var = s2v[ci]*invE - mean[ci]*mean[ci];
      rstd[ci]=rsqrtf(var+BN_EPS);
      gg[ci]=ggv[ci]; bb[ci]=bbv[ci];
    }
  }
  float ein[4][4];
  #pragma unroll
  for(int ci=0;ci<4;++ci){
    const float4 q = *reinterpret_cast<const float4*>(&At[c0+ci][r0]);
    ein[0][ci]=q.x; ein[1][ci]=q.y; ein[2][ci]=q.z; ein[3][ci]=q.w;
  }
  #pragma unroll
  for(int ri=0;ri<4;++ri){
    const float4 bh4 = *reinterpret_cast<const float4*>(&Bh[(size_t)dstI[ri]*64 + c0]);
    const float4 ch4 = *reinterpret_cast<const float4*>(&Ch[(size_t)srcI[ri]*64 + c0]);
    const float bh[4]={bh4.x,bh4.y,bh4.z,bh4.w};
    const float ch[4]={ch4.x,ch4.y,ch4.z,ch4.w};
    unsigned int pk[2];
    #pragma unroll
    for(int p=0;p<2;++p){
      float o0, o1;
      {
        int ci=2*p;
        float t = acc[ri][ci] + ab[ci] + bh[ci] + ch[ci];
        float v = (t-mean[ci])*rstd[ci]*gg[ci] + bb[ci];
        o0 = ein[ri][ci] + fmaxf(v, 0.0f);
        ci=2*p+1;
        t = acc[ri][ci] + ab[ci] + bh[ci] + ch[ci];
        v = (t-mean[ci])*rstd[ci]*gg[ci] + bb[ci];
        o1 = ein[ri][ci] + fmaxf(v, 0.0f);
      }
      pk[p] = (unsigned int)f2bf(o0) | ((unsigned int)f2bf(o1)<<16);
    }
    *reinterpret_cast<uint2*>(&e[(size_t)(row0+r0+ri)*64 + c0]) = make_uint2(pk[0], pk[1]);
  }
}

// ---------------------------------------------------------- final MLP (fused)
__global__ __launch_bounds__(256) void k_mlp(
    const unsigned short* __restrict__ e,
    const int* __restrict__ eidP,
    const float* __restrict__ f1w, const float* __restrict__ f1b,
    const float* __restrict__ f2w, const float* __restrict__ f2b,
    const float* __restrict__ f3w, const float* __restrict__ f3b,
    float* __restrict__ out)
{
  __shared__ float At[64][68];
  __shared__ float Ws[64][68];
  __shared__ float ored[64];
  const int tid=threadIdx.x;
  const int row0 = blockIdx.x*64;
  if(tid<64) ored[tid]=0.f;
  stage_At_bf16(At, e, row0, tid);
  stage_W(Ws, f1w, tid);
  __syncthreads();
  const int tx=tid&15, ty=tid>>4, r0=tx<<2, c0=ty<<2;
  float acc[4][4]={{0.f}};
  tile_gemm(At, Ws, r0, c0, acc);
  const float4 b14 = *reinterpret_cast<const float4*>(&f1b[c0]);
  const float b1[4]={b14.x,b14.y,b14.z,b14.w};
  float z1[4][4];
  #pragma unroll
  for(int ri=0;ri<4;++ri)
    #pragma unroll
    for(int ci=0;ci<4;++ci){
      float v = acc[ri][ci]+b1[ci];
      z1[ri][ci] = v*sigf(v);
    }
  __syncthreads();
  #pragma unroll
  for(int ri=0;ri<4;++ri)
    #pragma unroll
    for(int ci=0;ci<4;++ci)
      At[c0+ci][r0+ri] = z1[ri][ci];
  stage_W(Ws, f2w, tid);
  __syncthreads();
  float acc2[4][4]={{0.f}};
  tile_gemm(At, Ws, r0, c0, acc2);
  const float4 b24 = *reinterpret_cast<const float4*>(&f2b[c0]);
  const float b2[4]={b24.x,b24.y,b24.z,b24.w};
  const float4 w34 = *reinterpret_cast<const float4*>(&f3w[c0]);
  const float w3[4]={w34.x,w34.y,w34.z,w34.w};
  float part[4]={0.f,0.f,0.f,0.f};
  #pragma unroll
  for(int ri=0;ri<4;++ri)
    #pragma unroll
    for(int ci=0;ci<4;++ci){
      float v = acc2[ri][ci]+b2[ci];
      float z = v*sigf(v);
      part[ri] += z*w3[ci];
    }
  #pragma unroll
  for(int ri=0;ri<4;++ri) atomicAdd(&ored[r0+ri], part[ri]);
  __syncthreads();
  if(tid<64) out[eidP[row0+tid]] = sigf(ored[tid] + f3b[0]);
}

// ---------------------------------------------------------------- launch
extern "C" void kernel_launch(void* const* d_in, const int* in_sizes, int n_in,
                              void* d_out, int out_size, void* d_ws, size_t ws_size,
                              hipStream_t stream){
  const float* x    = (const float*)d_in[0];
  const float* ea   = (const float*)d_in[1];
  const int*   ei   = (const int*)  d_in[2];
  const float* hp_w = (const float*)d_in[3];
  const float* hp_b = (const float*)d_in[4];
  const float* ep_w = (const float*)d_in[5];
  const float* ep_b = (const float*)d_in[6];
  const float* Uw   = (const float*)d_in[7];
  const float* Ub   = (const float*)d_in[8];
  const float* Vw   = (const float*)d_in[9];
  const float* Vb   = (const float*)d_in[10];
  const float* Aw   = (const float*)d_in[11];
  const float* Ab   = (const float*)d_in[12];
  const float* Bw   = (const float*)d_in[13];
  const float* Bb   = (const float*)d_in[14];
  const float* Cw   = (const float*)d_in[15];
  const float* Cb   = (const float*)d_in[16];
  const float* hg   = (const float*)d_in[17];
  const float* hb   = (const float*)d_in[18];
  const float* eg   = (const float*)d_in[19];
  const float* eb   = (const float*)d_in[20];
  const float* f1w  = (const float*)d_in[21];
  const float* f1b  = (const float*)d_in[22];
  const float* f2w  = (const float*)d_in[23];
  const float* f2b  = (const float*)d_in[24];
  const float* f3w  = (const float*)d_in[25];
  const float* f3b  = (const float*)d_in[26];

  // ws: e(bf16 NE) | h,Uh,Vh,Bh,Ch (f32 NH) | stats(256) | cnt | invc | row_ptr | cursor | eidP | dstP | srcP
  char* base = (char*)d_ws;
  unsigned short* e = (unsigned short*)base;            // 102.4 MB
  float* h     = (float*)(base + (size_t)NE*2);
  float* Uh    = h  + (size_t)NH;
  float* Vh    = h  + 2ull*NH;
  float* Bh    = h  + 3ull*NH;
  float* Ch    = h  + 4ull*NH;
  float* stats = h  + 5ull*NH;            // 256 floats
  int*   cnt     = (int*)(stats + 256);   // NNODE
  float* invc    = (float*)(cnt + NNODE); // NNODE
  int*   row_ptr = (int*)(invc + NNODE);  // NNODE+1
  int*   cursor  = row_ptr + NNODE + 1;   // NNODE
  int*   eidP    = cursor + NNODE;        // NEDGE
  int*   dstP    = eidP + NEDGE;          // NEDGE
  int*   srcP    = dstP + NEDGE;          // NEDGE
  // total ≈ 177 MB

  dim3 blk(256);
  k_zero_i<<<dim3((NNODE+255)/256), blk, 0, stream>>>(cnt, NNODE);
  k_count <<<dim3((NEDGE+255)/256), blk, 0, stream>>>(ei, cnt);
  k_inv   <<<dim3((NNODE+255)/256), blk, 0, stream>>>(cnt, invc);
  k_scan  <<<dim3(1), blk, 0, stream>>>(cnt, row_ptr, cursor);
  k_fill  <<<dim3((NEDGE+255)/256), blk, 0, stream>>>(ei, cursor, eidP);
  k_perm  <<<dim3((NEDGE+255)/256), blk, 0, stream>>>(ei, eidP, dstP, srcP);
  k_init_h<<<dim3((NH+255)/256), blk, 0, stream>>>(x, hp_w, hp_b, h);
  k_init_e<<<dim3((NE/2+255)/256), blk, 0, stream>>>(ea, eidP, ep_w, ep_b, e);

  for(int l=0;l<NLAYER;++l){
    k_zero_stats<<<dim3(1), blk, 0, stream>>>(stats);
    k_node_gemm<<<dim3((NNODE+63)/64), blk, 0, stream>>>(h,
        Uw+l*4096, Ub+l*64, Vw+l*4096, Vb+l*64,
        Bw+l*4096, Bb+l*64, Cw+l*4096, Cb+l*64,
        Uh, Vh, Bh, Ch);
    k_edge_A<<<dim3(NEDGE/64), blk, 0, stream>>>(e, Aw+l*4096, Ab+l*64,
        Bh, Ch, dstP, srcP, stats);
    k_agg<<<dim3(NNODE/4), blk, 0, stream>>>(e, Vh, srcP, row_ptr,
        invc, Uh, stats);
    k_node_finB<<<dim3(NH/256), blk, 0, stream>>>(Uh, h, stats, hg+l*64, hb+l*64);
    k_edge_B<<<dim3(NEDGE/64), blk, 0, stream>>>(e, Aw+l*4096, Ab+l*64,
        Bh, Ch, dstP, srcP, stats, eg+l*64, eb+l*64);
  }
  k_mlp<<<dim3(NEDGE/64), blk, 0, stream>>>(e, eidP, f1w, f1b, f2w, f2b,
                                            f3w, f3b, (float*)d_out);
}

// Round 9
// 3791.171 us; speedup vs baseline: 1.0651x; 1.0651x over previous
//
#include <hip/hip_runtime.h>

#define NNODE 50000
#define NEDGE 800000
#define NLAYER 4
#define BN_EPS 1e-5f

#define NH (NNODE*64)   // 3,200,000
#define NE (NEDGE*64)   // 51,200,000

typedef __attribute__((ext_vector_type(8))) short short8v;
typedef unsigned short us;

__device__ __forceinline__ float sigf(float x){ return 1.0f/(1.0f+__expf(-x)); }

// bf16 helpers (e state)
__device__ __forceinline__ float bf2f(us u){
  union { unsigned int i; float f; } c; c.i = ((unsigned int)u)<<16; return c.f;
}
__device__ __forceinline__ us f2bf(float f){
  union { float f; unsigned int i; } c; c.f = f;
  unsigned int r = c.i + 0x7FFFu + ((c.i>>16)&1u);   // RNE
  return (us)(r>>16);
}
// fp16 helpers (t, Vh, Bh, Ch)
__device__ __forceinline__ float hf2f(us u){
  union { us u; _Float16 h; } c; c.u=u; return (float)c.h;
}
__device__ __forceinline__ us f2hf(float f){
  union { us u; _Float16 h; } c; c.h=(_Float16)f; return c.u;
}

// ---------------------------------------------------------------- utility
__global__ void k_zero_i(int* __restrict__ p, int n){
  int i = blockIdx.x*256 + threadIdx.x;
  if(i<n) p[i]=0;
}
__global__ void k_zero_stats(float* __restrict__ stats){
  stats[threadIdx.x] = 0.f;   // one block of 256
}
__global__ void k_count(const int* __restrict__ ei, int* __restrict__ cnt){
  int i = blockIdx.x*256 + threadIdx.x;
  if(i<NEDGE) atomicAdd(&cnt[ei[i]], 1);   // ei[0][i] = dst
}
__global__ void k_inv(const int* __restrict__ cnt, float* __restrict__ invc){
  int i = blockIdx.x*256 + threadIdx.x;
  if(i<NNODE){ int c=cnt[i]; invc[i] = 1.0f/(float)(c<1?1:c); }
}

// single-block exclusive scan of cnt -> row_ptr (+cursor copy)
__global__ void k_scan(const int* __restrict__ cnt, int* __restrict__ row_ptr,
                       int* __restrict__ cursor){
  __shared__ int buf[256];
  __shared__ int carry;
  const int tid = threadIdx.x;
  if(tid==0) carry=0;
  __syncthreads();
  for(int base=0; base<NNODE; base+=256){
    int i = base+tid;
    int v = (i<NNODE)? cnt[i] : 0;
    buf[tid]=v; __syncthreads();
    #pragma unroll
    for(int off=1; off<256; off<<=1){
      int t = (tid>=off)? buf[tid-off] : 0;
      __syncthreads();
      buf[tid]+=t;
      __syncthreads();
    }
    int excl = carry + buf[tid]-v;
    if(i<NNODE){ row_ptr[i]=excl; cursor[i]=excl; }
    __syncthreads();
    if(tid==0) carry += buf[255];
    __syncthreads();
  }
  if(tid==0) row_ptr[NNODE]=carry;
}

__global__ void k_fill(const int* __restrict__ ei, int* __restrict__ cursor,
                       int* __restrict__ eidP){
  int i = blockIdx.x*256 + threadIdx.x;
  if(i<NEDGE){
    int pos = atomicAdd(&cursor[ei[i]], 1);
    eidP[pos] = i;
  }
}

__global__ void k_perm(const int* __restrict__ ei, const int* __restrict__ eidP,
                       int* __restrict__ dstP, int* __restrict__ srcP){
  int p = blockIdx.x*256 + threadIdx.x;
  if(p<NEDGE){
    int eid = eidP[p];
    dstP[p] = ei[eid];
    srcP[p] = ei[NEDGE+eid];
  }
}

__global__ void k_init_h(const float* __restrict__ x, const float* __restrict__ w,
                         const float* __restrict__ b, float* __restrict__ h){
  int t = blockIdx.x*256 + threadIdx.x;
  if(t>=NH) return;
  int i=t>>6, j=t&63;
  float v = x[2*i]*w[j] + x[2*i+1]*w[64+j] + b[j];
  h[t] = fmaxf(v, 0.0f);
}

__global__ void k_init_e(const float* __restrict__ ea, const int* __restrict__ eidP,
                         const float* __restrict__ w, const float* __restrict__ b,
                         us* __restrict__ e){
  int t = blockIdx.x*256 + threadIdx.x;      // pair index
  if(t >= NE/2) return;
  int p = t>>5;          // slot
  int j = (t&31)<<1;
  float a = ea[eidP[p]];
  float v0 = fmaxf(a*w[j]   + b[j],   0.f);
  float v1 = fmaxf(a*w[j+1] + b[j+1], 0.f);
  unsigned int pk = (unsigned int)f2bf(v0) | ((unsigned int)f2bf(v1)<<16);
  *reinterpret_cast<unsigned int*>(&e[2*t]) = pk;
}

// ------------------------------------------------------------ tile helpers
__device__ __forceinline__ void tile_gemm(const float (&At)[64][68], const float (&Ws)[64][68],
                                          int r0, int c0, float (&acc)[4][4]){
  #pragma unroll 4
  for(int k=0;k<64;++k){
    const float4 a = *reinterpret_cast<const float4*>(&At[k][r0]);
    const float4 b = *reinterpret_cast<const float4*>(&Ws[k][c0]);
    const float av[4]={a.x,a.y,a.z,a.w};
    const float bv[4]={b.x,b.y,b.z,b.w};
    #pragma unroll
    for(int ri=0;ri<4;++ri)
      #pragma unroll
      for(int ci=0;ci<4;++ci)
        acc[ri][ci] = fmaf(av[ri], bv[ci], acc[ri][ci]);
  }
}

__device__ __forceinline__ void stage_At_f32(float (&At)[64][68], const float* __restrict__ src,
                                             int row0, int rowmax, int tid){
  for(int it=0; it<4; ++it){
    int idx = tid + it*256;
    int r = idx>>4, c4=(idx&15)<<2;
    int gr = row0 + r;
    float4 v = make_float4(0.f,0.f,0.f,0.f);
    if(gr < rowmax) v = *reinterpret_cast<const float4*>(&src[(size_t)gr*64 + c4]);
    At[c4+0][r]=v.x; At[c4+1][r]=v.y; At[c4+2][r]=v.z; At[c4+3][r]=v.w;
  }
}

__device__ __forceinline__ void stage_At_bf16(float (&At)[64][68], const us* __restrict__ src,
                                              int row0, int tid){
  #pragma unroll
  for(int it=0; it<2; ++it){
    int idx = tid + it*256;          // 0..511
    int r = idx>>3, c8 = (idx&7)<<3;
    int gr = row0 + r;
    const short8v v = *reinterpret_cast<const short8v*>(&src[(size_t)gr*64 + c8]);
    #pragma unroll
    for(int j=0;j<8;++j) At[c8+j][r] = bf2f((us)v[j]);
  }
}

__device__ __forceinline__ void stage_W(float (&Ws)[64][68], const float* __restrict__ W, int tid){
  for(int it=0; it<4; ++it){
    int idx = tid + it*256;
    int k = idx>>4, c4=(idx&15)<<2;
    *reinterpret_cast<float4*>(&Ws[k][c4]) = *reinterpret_cast<const float4*>(&W[k*64+c4]);
  }
}

// ---------------------------------------------------------- node GEMMs
// Uh -> f32; Vh/Bh/Ch -> f16
__device__ __forceinline__ void node_one_mat_f32(float (&At)[64][68], float (&Ws)[64][68],
    const float* __restrict__ W, const float* __restrict__ B, float* __restrict__ O,
    int row0, int tid){
  __syncthreads();
  stage_W(Ws, W, tid);
  __syncthreads();
  const int tx=tid&15, ty=tid>>4, r0=tx<<2, c0=ty<<2;
  float acc[4][4]={{0.f}};
  tile_gemm(At, Ws, r0, c0, acc);
  const float4 b4 = *reinterpret_cast<const float4*>(&B[c0]);
  const float bb[4]={b4.x,b4.y,b4.z,b4.w};
  #pragma unroll
  for(int ri=0;ri<4;++ri){
    int gr = row0 + r0 + ri;
    if(gr < NNODE){
      float4 o = make_float4(acc[ri][0]+bb[0], acc[ri][1]+bb[1],
                             acc[ri][2]+bb[2], acc[ri][3]+bb[3]);
      *reinterpret_cast<float4*>(&O[(size_t)gr*64 + c0]) = o;
    }
  }
}

__device__ __forceinline__ void node_one_mat_f16(float (&At)[64][68], float (&Ws)[64][68],
    const float* __restrict__ W, const float* __restrict__ B, us* __restrict__ O,
    int row0, int tid){
  __syncthreads();
  stage_W(Ws, W, tid);
  __syncthreads();
  const int tx=tid&15, ty=tid>>4, r0=tx<<2, c0=ty<<2;
  float acc[4][4]={{0.f}};
  tile_gemm(At, Ws, r0, c0, acc);
  const float4 b4 = *reinterpret_cast<const float4*>(&B[c0]);
  const float bb[4]={b4.x,b4.y,b4.z,b4.w};
  #pragma unroll
  for(int ri=0;ri<4;++ri){
    int gr = row0 + r0 + ri;
    if(gr < NNODE){
      unsigned int p0 = (unsigned int)f2hf(acc[ri][0]+bb[0]) | ((unsigned int)f2hf(acc[ri][1]+bb[1])<<16);
      unsigned int p1 = (unsigned int)f2hf(acc[ri][2]+bb[2]) | ((unsigned int)f2hf(acc[ri][3]+bb[3])<<16);
      *reinterpret_cast<uint2*>(&O[(size_t)gr*64 + c0]) = make_uint2(p0,p1);
    }
  }
}

__global__ __launch_bounds__(256) void k_node_gemm(
    const float* __restrict__ h,
    const float* __restrict__ Uw, const float* __restrict__ Ub,
    const float* __restrict__ Vw, const float* __restrict__ Vb,
    const float* __restrict__ Bw, const float* __restrict__ Bb,
    const float* __restrict__ Cw, const float* __restrict__ Cb,
    float* __restrict__ Uh, us* __restrict__ Vh,
    us* __restrict__ Bh, us* __restrict__ Ch)
{
  __shared__ float At[64][68];
  __shared__ float Ws[64][68];
  const int tid = threadIdx.x;
  const int row0 = blockIdx.x*64;
  stage_At_f32(At, h, row0, NNODE, tid);
  node_one_mat_f32(At, Ws, Uw, Ub, Uh, row0, tid);
  node_one_mat_f16(At, Ws, Vw, Vb, Vh, row0, tid);
  node_one_mat_f16(At, Ws, Bw, Bb, Bh, row0, tid);
  node_one_mat_f16(At, Ws, Cw, Cb, Ch, row0, tid);
}

// ---------------------------------------------------------- edge pass A
// t = e@Aw + Ab + Bh[dstP] + Ch[srcP]; store t (f16); accumulate e-BN stats.
__global__ __launch_bounds__(256) void k_edge_A(
    const us* __restrict__ e,
    const float* __restrict__ Aw, const float* __restrict__ Ab,
    const us* __restrict__ Bh, const us* __restrict__ Ch,
    const int* __restrict__ dstP, const int* __restrict__ srcP,
    us* __restrict__ t16, float* __restrict__ stats)
{
  __shared__ float At[64][68];
  __shared__ float Ws[64][68];
  __shared__ float red[128];
  const int tid=threadIdx.x;
  const int row0 = blockIdx.x*64;
  if(tid<128) red[tid]=0.f;
  stage_At_bf16(At, e, row0, tid);
  stage_W(Ws, Aw, tid);
  __syncthreads();
  const int tx=tid&15, ty=tid>>4, r0=tx<<2, c0=ty<<2;
  float acc[4][4]={{0.f}};
  tile_gemm(At, Ws, r0, c0, acc);

  int dstI[4], srcI[4];
  #pragma unroll
  for(int ri=0;ri<4;++ri){
    dstI[ri]=dstP[row0+r0+ri];
    srcI[ri]=srcP[row0+r0+ri];
  }
  const float4 ab4 = *reinterpret_cast<const float4*>(&Ab[c0]);
  const float ab[4]={ab4.x,ab4.y,ab4.z,ab4.w};

  float s1[4]={0.f,0.f,0.f,0.f}, s2[4]={0.f,0.f,0.f,0.f};
  #pragma unroll
  for(int ri=0;ri<4;++ri){
    const uint2 b2 = *reinterpret_cast<const uint2*>(&Bh[(size_t)dstI[ri]*64 + c0]);
    const uint2 c2 = *reinterpret_cast<const uint2*>(&Ch[(size_t)srcI[ri]*64 + c0]);
    const float bh[4]={hf2f((us)(b2.x&0xffff)), hf2f((us)(b2.x>>16)),
                       hf2f((us)(b2.y&0xffff)), hf2f((us)(b2.y>>16))};
    const float ch[4]={hf2f((us)(c2.x&0xffff)), hf2f((us)(c2.x>>16)),
                       hf2f((us)(c2.y&0xffff)), hf2f((us)(c2.y>>16))};
    float tv[4];
    #pragma unroll
    for(int ci=0;ci<4;++ci){
      float t = acc[ri][ci] + ab[ci] + bh[ci] + ch[ci];
      tv[ci]=t;
      s1[ci]+=t; s2[ci]+=t*t;
    }
    unsigned int p0 = (unsigned int)f2hf(tv[0]) | ((unsigned int)f2hf(tv[1])<<16);
    unsigned int p1 = (unsigned int)f2hf(tv[2]) | ((unsigned int)f2hf(tv[3])<<16);
    *reinterpret_cast<uint2*>(&t16[(size_t)(row0+r0+ri)*64 + c0]) = make_uint2(p0,p1);
  }
  #pragma unroll
  for(int ci=0;ci<4;++ci){
    atomicAdd(&red[c0+ci],    s1[ci]);
    atomicAdd(&red[64+c0+ci], s2[ci]);
  }
  __syncthreads();
  if(tid<64){
    atomicAdd(&stats[tid],    red[tid]);
    atomicAdd(&stats[64+tid], red[64+tid]);
  }
}

// ---------------------------------------------------------- CSR aggregation + h-BN stats
__global__ __launch_bounds__(256) void k_agg(
    const us* __restrict__ e,
    const us* __restrict__ Vh,
    const int* __restrict__ srcP,
    const int* __restrict__ row_ptr,
    const float* __restrict__ invc,
    float* __restrict__ Uh, float* __restrict__ stats)
{
  __shared__ float red[128];
  const int tid=threadIdx.x;
  if(tid<128) red[tid]=0.f;
  __syncthreads();
  const int lane = tid&63;
  const int node = blockIdx.x*4 + (tid>>6);   // 4 waves/block
  const int beg = row_ptr[node];
  const int end = row_ptr[node+1];
  float acc = 0.f;
  for(int p=beg; p<end; ++p){
    int src = srcP[p];
    float g = sigf(bf2f(e[(size_t)p*64 + lane]));
    acc = fmaf(g, hf2f(Vh[(size_t)src*64 + lane]), acc);
  }
  size_t o = (size_t)node*64 + lane;
  float val = Uh[o] + acc*invc[node];
  Uh[o] = val;
  atomicAdd(&red[lane], val);
  atomicAdd(&red[64+lane], val*val);
  __syncthreads();
  if(tid<128) atomicAdd(&stats[128+tid], red[tid]);
}

__global__ void k_node_finB(const float* __restrict__ th, float* __restrict__ h,
                            const float* __restrict__ stats,
                            const float* __restrict__ hg, const float* __restrict__ hb){
  int t = blockIdx.x*256 + threadIdx.x;
  if(t>=NH) return;
  int j=t&63;
  const float invN = 1.0f/(float)NNODE;
  float mean = stats[128+j]*invN;
  float var  = stats[192+j]*invN - mean*mean;
  float rstd = rsqrtf(var + BN_EPS);
  float v = (th[t]-mean)*rstd*hg[j] + hb[j];
  h[t] += fmaxf(v, 0.0f);
}

// ---------------------------------------------------------- edge BN finalize (elementwise)
// e = e + relu(t*a + b), a = rstd*gamma, b = beta - mean*a
__global__ __launch_bounds__(256) void k_ebn(
    const us* __restrict__ t16,
    const float* __restrict__ stats,
    const float* __restrict__ eg, const float* __restrict__ eb,
    us* __restrict__ e)
{
  __shared__ float a_s[64], b_s[64];
  const int tid=threadIdx.x;
  if(tid<64){
    const float invE = 1.0f/(float)NEDGE;
    float mean = stats[tid]*invE;
    float var  = stats[64+tid]*invE - mean*mean;
    float rstd = rsqrtf(var + BN_EPS);
    float a = rstd*eg[tid];
    a_s[tid]=a;
    b_s[tid]=eb[tid]-mean*a;
  }
  __syncthreads();
  size_t idx = (size_t)blockIdx.x*256 + tid;   // NE/8 threads
  int j0 = ((int)idx&7)<<3;
  const short8v tv = *reinterpret_cast<const short8v*>(&t16[idx*8]);
  const short8v ev = *reinterpret_cast<const short8v*>(&e[idx*8]);
  short8v ov;
  #pragma unroll
  for(int j=0;j<8;++j){
    float tt = hf2f((us)tv[j]);
    float v  = tt*a_s[j0+j] + b_s[j0+j];
    float o  = bf2f((us)ev[j]) + fmaxf(v, 0.0f);
    ov[j] = (short)f2bf(o);
  }
  *reinterpret_cast<short8v*>(&e[idx*8]) = ov;
}

// ---------------------------------------------------------- final MLP (fused)
__global__ __launch_bounds__(256) void k_mlp(
    const us* __restrict__ e,
    const int* __restrict__ eidP,
    const float* __restrict__ f1w, const float* __restrict__ f1b,
    const float* __restrict__ f2w, const float* __restrict__ f2b,
    const float* __restrict__ f3w, const float* __restrict__ f3b,
    float* __restrict__ out)
{
  __shared__ float At[64][68];
  __shared__ float Ws[64][68];
  __shared__ float ored[64];
  const int tid=threadIdx.x;
  const int row0 = blockIdx.x*64;
  if(tid<64) ored[tid]=0.f;
  stage_At_bf16(At, e, row0, tid);
  stage_W(Ws, f1w, tid);
  __syncthreads();
  const int tx=tid&15, ty=tid>>4, r0=tx<<2, c0=ty<<2;
  float acc[4][4]={{0.f}};
  tile_gemm(At, Ws, r0, c0, acc);
  const float4 b14 = *reinterpret_cast<const float4*>(&f1b[c0]);
  const float b1[4]={b14.x,b14.y,b14.z,b14.w};
  float z1[4][4];
  #pragma unroll
  for(int ri=0;ri<4;++ri)
    #pragma unroll
    for(int ci=0;ci<4;++ci){
      float v = acc[ri][ci]+b1[ci];
      z1[ri][ci] = v*sigf(v);
    }
  __syncthreads();
  #pragma unroll
  for(int ri=0;ri<4;++ri)
    #pragma unroll
    for(int ci=0;ci<4;++ci)
      At[c0+ci][r0+ri] = z1[ri][ci];
  stage_W(Ws, f2w, tid);
  __syncthreads();
  float acc2[4][4]={{0.f}};
  tile_gemm(At, Ws, r0, c0, acc2);
  const float4 b24 = *reinterpret_cast<const float4*>(&f2b[c0]);
  const float b2[4]={b24.x,b24.y,b24.z,b24.w};
  const float4 w34 = *reinterpret_cast<const float4*>(&f3w[c0]);
  const float w3[4]={w34.x,w34.y,w34.z,w34.w};
  float part[4]={0.f,0.f,0.f,0.f};
  #pragma unroll
  for(int ri=0;ri<4;++ri)
    #pragma unroll
    for(int ci=0;ci<4;++ci){
      float v = acc2[ri][ci]+b2[ci];
      float z = v*sigf(v);
      part[ri] += z*w3[ci];
    }
  #pragma unroll
  for(int ri=0;ri<4;++ri) atomicAdd(&ored[r0+ri], part[ri]);
  __syncthreads();
  if(tid<64) out[eidP[row0+tid]] = sigf(ored[tid] + f3b[0]);
}

// ---------------------------------------------------------------- launch
extern "C" void kernel_launch(void* const* d_in, const int* in_sizes, int n_in,
                              void* d_out, int out_size, void* d_ws, size_t ws_size,
                              hipStream_t stream){
  const float* x    = (const float*)d_in[0];
  const float* ea   = (const float*)d_in[1];
  const int*   ei   = (const int*)  d_in[2];
  const float* hp_w = (const float*)d_in[3];
  const float* hp_b = (const float*)d_in[4];
  const float* ep_w = (const float*)d_in[5];
  const float* ep_b = (const float*)d_in[6];
  const float* Uw   = (const float*)d_in[7];
  const float* Ub   = (const float*)d_in[8];
  const float* Vw   = (const float*)d_in[9];
  const float* Vb   = (const float*)d_in[10];
  const float* Aw   = (const float*)d_in[11];
  const float* Ab   = (const float*)d_in[12];
  const float* Bw   = (const float*)d_in[13];
  const float* Bb   = (const float*)d_in[14];
  const float* Cw   = (const float*)d_in[15];
  const float* Cb   = (const float*)d_in[16];
  const float* hg   = (const float*)d_in[17];
  const float* hb   = (const float*)d_in[18];
  const float* eg   = (const float*)d_in[19];
  const float* eb   = (const float*)d_in[20];
  const float* f1w  = (const float*)d_in[21];
  const float* f1b  = (const float*)d_in[22];
  const float* f2w  = (const float*)d_in[23];
  const float* f2b  = (const float*)d_in[24];
  const float* f3w  = (const float*)d_in[25];
  const float* f3b  = (const float*)d_in[26];

  // ws: e(bf16) | t(f16) | h(f32) | Uh(f32) | stats | Vh/Bh/Ch(f16) | int arrays
  char* base = (char*)d_ws;
  us* e    = (us*)base;                               // 102.4 MB
  us* t16  = (us*)(base + (size_t)NE*2);              // 102.4 MB
  float* h  = (float*)(base + 2ull*NE*2);             // 12.8 MB
  float* Uh = h + (size_t)NH;                         // 12.8 MB
  float* stats = Uh + (size_t)NH;                     // 1 KB
  us* Vh = (us*)(stats + 256);                        // 6.4 MB
  us* Bh = Vh + (size_t)NH;                           // 6.4 MB
  us* Ch = Bh + (size_t)NH;                           // 6.4 MB
  int* cnt     = (int*)(Ch + (size_t)NH);             // 0.2 MB
  float* invc  = (float*)(cnt + NNODE);
  int* row_ptr = (int*)(invc + NNODE);
  int* cursor  = row_ptr + NNODE + 1;
  int* eidP    = cursor + NNODE;                      // 3.2 MB
  int* dstP    = eidP + NEDGE;                        // 3.2 MB
  int* srcP    = dstP + NEDGE;                        // 3.2 MB
  // total ≈ 260.0 MB

  dim3 blk(256);
  k_zero_i<<<dim3((NNODE+255)/256), blk, 0, stream>>>(cnt, NNODE);
  k_count <<<dim3((NEDGE+255)/256), blk, 0, stream>>>(ei, cnt);
  k_inv   <<<dim3((NNODE+255)/256), blk, 0, stream>>>(cnt, invc);
  k_scan  <<<dim3(1), blk, 0, stream>>>(cnt, row_ptr, cursor);
  k_fill  <<<dim3((NEDGE+255)/256), blk, 0, stream>>>(ei, cursor, eidP);
  k_perm  <<<dim3((NEDGE+255)/256), blk, 0, stream>>>(ei, eidP, dstP, srcP);
  k_init_h<<<dim3((NH+255)/256), blk, 0, stream>>>(x, hp_w, hp_b, h);
  k_init_e<<<dim3((NE/2+255)/256), blk, 0, stream>>>(ea, eidP, ep_w, ep_b, e);

  for(int l=0;l<NLAYER;++l){
    k_zero_stats<<<dim3(1), blk, 0, stream>>>(stats);
    k_node_gemm<<<dim3((NNODE+63)/64), blk, 0, stream>>>(h,
        Uw+l*4096, Ub+l*64, Vw+l*4096, Vb+l*64,
        Bw+l*4096, Bb+l*64, Cw+l*4096, Cb+l*64,
        Uh, Vh, Bh, Ch);
    k_edge_A<<<dim3(NEDGE/64), blk, 0, stream>>>(e, Aw+l*4096, Ab+l*64,
        Bh, Ch, dstP, srcP, t16, stats);
    k_agg<<<dim3(NNODE/4), blk, 0, stream>>>(e, Vh, srcP, row_ptr,
        invc, Uh, stats);
    k_node_finB<<<dim3(NH/256), blk, 0, stream>>>(Uh, h, stats, hg+l*64, hb+l*64);
    k_ebn<<<dim3(NE/8/256), blk, 0, stream>>>(t16, stats, eg+l*64, eb+l*64, e);
  }
  k_mlp<<<dim3(NEDGE/64), blk, 0, stream>>>(e, eidP, f1w, f1b, f2w, f2b,
                                            f3w, f3b, (float*)d_out);
}